// Round 2
// 957.364 us; speedup vs baseline: 1.0052x; 1.0052x over previous
//
#include <hip/hip_runtime.h>

// CCN layer promotion: promotions[n,c,a,b,s] = chi[n,c,a]*chi[n,c,b]*feat[n,c,s]
// where chi[n,c,a] = (neigh[n,a] == neigh[n,c]), feat[n,c,:] = tensors[neigh[n,c],:].
// neigh is pre-sorted by setup, so new_parts == neigh (output 1, written as float).
//
// Timing model (R0 counters): timed graph = harness poison-fill (~636us, untouchable)
// + this kernel (~326us = 984 MB stores at 3.05 TB/s). R2 lever: non-temporal
// stores (bypass L2 write-allocate churn: 984 MB streaming through 32 MB L2)
// + 2-node blocks to lengthen each CU's sequential write stream.
// R1->R2 fix: __builtin_nontemporal_store needs a clang ext_vector, not HIP float4.

constexpr int NN = 20000;
constexpr int DD = 16;
constexpr int FF = 3;
constexpr int PROMO_PER_NODE = DD * DD * DD * FF;                 // 12288 floats
constexpr long long PROMO_TOTAL = (long long)NN * PROMO_PER_NODE; // 245,760,000

constexpr int NODES_PER_BLOCK = 2;
constexpr int THREADS = 192 * NODES_PER_BLOCK;  // 384 = 6 waves; 5 blocks/CU -> 93.75% occ

typedef float v4f __attribute__((ext_vector_type(4)));  // native vector for nt-store

// Per-node 192-lane mapping (unchanged from verified R0 kernel):
// float4 index q = c*192 + tt  ->  a = tt/12 (slot), k = tt%12 (float4 within 48-float slab).
// 192 % 12 == 0, so (a,k) are per-thread constants and c is the loop counter.
__global__ __launch_bounds__(THREADS) void ccn_promote_kernel(
    const float* __restrict__ tensors,
    const int* __restrict__ neigh,
    float* __restrict__ out)
{
    const int t  = threadIdx.x;
    const int bn = blockIdx.x * NODES_PER_BLOCK;   // first node of this block

    __shared__ int   nv[NODES_PER_BLOCK * DD];
    __shared__ float fv[NODES_PER_BLOCK * DD][4];  // feature rows padded to 4

    if (t < NODES_PER_BLOCK * DD) {
        const int id = neigh[bn * DD + t];         // 32 contiguous ints: coalesced
        nv[t] = id;
        // output 1: new_parts (== sorted neigh) as float, streaming store
        __builtin_nontemporal_store((float)id,
            out + (size_t)PROMO_TOTAL + (size_t)bn * DD + t);
        const float* src = tensors + (size_t)id * FF;  // 240 KB table: L2-resident gather
        fv[t][0] = src[0];
        fv[t][1] = src[1];
        fv[t][2] = src[2];
        fv[t][3] = 0.0f;
    }
    __syncthreads();

    const int g  = t / 192;      // node within block; 192 = 3*64 -> wave-uniform
    const int tt = t % 192;
    const int a  = tt / 12;      // slot index 0..15
    const int k  = tt % 12;      // which float4 within the 48-float (c,a) slab
    const int e0 = 4 * k;        // first flat element (3b+s) in this float4

    const int s0 = (e0 + 0) % 3, b0 = (e0 + 0) / 3;
    const int s1 = (e0 + 1) % 3, b1 = (e0 + 1) / 3;
    const int s2 = (e0 + 2) % 3, b2 = (e0 + 2) / 3;
    const int s3 = (e0 + 3) % 3, b3 = (e0 + 3) / 3;

    const int base = g * DD;
    const int nva  = nv[base + a];
    const int nvb0 = nv[base + b0];
    const int nvb1 = nv[base + b1];
    const int nvb2 = nv[base + b2];
    const int nvb3 = nv[base + b3];

    // hoist neigh row into registers (16 VGPRs) to keep the hot loop lean
    int nvc_r[DD];
#pragma unroll
    for (int i = 0; i < DD; ++i) nvc_r[i] = nv[base + i];

    v4f* outv = reinterpret_cast<v4f*>(out + (size_t)(bn + g) * PROMO_PER_NODE) + tt;

#pragma unroll
    for (int c = 0; c < DD; ++c) {
        const int  nvc = nvc_r[c];
        const bool ca  = (nva == nvc);
        v4f v;
        v.x = (ca && (nvb0 == nvc)) ? fv[base + c][s0] : 0.0f;
        v.y = (ca && (nvb1 == nvc)) ? fv[base + c][s1] : 0.0f;
        v.z = (ca && (nvb2 == nvc)) ? fv[base + c][s2] : 0.0f;
        v.w = (ca && (nvb3 == nvc)) ? fv[base + c][s3] : 0.0f;
        // coalesced streaming store: 192 lanes x 16B = 3KB contiguous per c
        __builtin_nontemporal_store(v, outv + c * 192);
    }
}

extern "C" void kernel_launch(void* const* d_in, const int* in_sizes, int n_in,
                              void* d_out, int out_size, void* d_ws, size_t ws_size,
                              hipStream_t stream) {
    const float* tensors = (const float*)d_in[0];  // [N, F] float32
    const int*   neigh   = (const int*)d_in[1];    // [N, D] int32 (sorted rows)
    float*       out     = (float*)d_out;          // promotions flat + new_parts flat

    ccn_promote_kernel<<<NN / NODES_PER_BLOCK, THREADS, 0, stream>>>(tensors, neigh, out);
}